// Round 1
// baseline (271.005 us; speedup 1.0000x reference)
//
#include <hip/hip_runtime.h>
#include <hip/hip_bf16.h>

// Problem constants (B,L,R,E,F fixed by reference setup_inputs)
#define NB 8
#define NL 128
#define NR 2048
#define NE 32
#define NF 64
#define RT 64                  // r-tile per block
#define EG 2                   // e's per block
#define NEG (NE / EG)          // 16 e-groups
#define NRT (NR / RT)          // 32 r-tiles
#define NTHREADS 256

typedef __attribute__((ext_vector_type(4))) float f32x4;
typedef __attribute__((ext_vector_type(8))) short s16x8;

__device__ __forceinline__ unsigned short f2bf(float x) {
    union { float f; unsigned u; } v; v.f = x;
    unsigned u = v.u;
    u += 0x7fffu + ((u >> 16) & 1u);   // round-to-nearest-even
    return (unsigned short)(u >> 16);
}

__global__ __launch_bounds__(NTHREADS, 3) void ff_kernel(
    const float* __restrict__ lig_feat,
    const float* __restrict__ rec_feat,
    const float* __restrict__ lig_coord,
    const float* __restrict__ rec_coord,
    float* __restrict__ out)
{
    // bf16 tiles, rows of 64 elems; 16B chunks XOR-swizzled by (row&7)
    __shared__ __align__(16) unsigned short sA[EG][NL * NF];  // 2 * 16 KB
    __shared__ __align__(16) unsigned short sB[EG][RT * NF];  // 2 *  8 KB
    __shared__ float sLc[3][NL];
    __shared__ float sRc[3][RT];
    __shared__ float sRed[NTHREADS / 64];

    const int blk = blockIdx.x;
    const int eg  = blk & (NEG - 1);
    const int rt  = (blk >> 4) & (NRT - 1);
    const int b   = blk >> 9;          // 4096 blocks = 8 * 32 * 16
    const int e0  = eg * EG;
    const int r0  = rt * RT;
    const int t   = threadIdx.x;

    // ---- stage features fp32 -> bf16 into LDS ----
    #pragma unroll
    for (int ke = 0; ke < EG; ++ke) {
        const int e = e0 + ke;
        const float* srcA = lig_feat + (((long)b * NL) * NE + e) * NF;
        for (int i = t; i < NL * NF / 4; i += NTHREADS) {
            const int l = i >> 4, f4 = i & 15;     // 16 float4 per row
            f32x4 v = *(const f32x4*)(srcA + (long)l * (NE * NF) + f4 * 4);
            const int pos = (((f4 >> 1) ^ (l & 7)) << 3) + ((f4 & 1) << 2);
            unsigned short* dst = &sA[ke][l * NF + pos];
            dst[0] = f2bf(v.x); dst[1] = f2bf(v.y);
            dst[2] = f2bf(v.z); dst[3] = f2bf(v.w);
        }
        const float* srcB = rec_feat + (((long)b * NR + r0) * NE + e) * NF;
        for (int i = t; i < RT * NF / 4; i += NTHREADS) {
            const int r = i >> 4, f4 = i & 15;
            f32x4 v = *(const f32x4*)(srcB + (long)r * (NE * NF) + f4 * 4);
            const int pos = (((f4 >> 1) ^ (r & 7)) << 3) + ((f4 & 1) << 2);
            unsigned short* dst = &sB[ke][r * NF + pos];
            dst[0] = f2bf(v.x); dst[1] = f2bf(v.y);
            dst[2] = f2bf(v.z); dst[3] = f2bf(v.w);
        }
    }
    // coords
    for (int i = t; i < 3 * NL; i += NTHREADS) {
        const int c = i >> 7, l = i & 127;
        sLc[c][l] = lig_coord[((long)b * NL + l) * 3 + c];
    }
    for (int i = t; i < 3 * RT; i += NTHREADS) {
        const int c = i >> 6, r = i & 63;
        sRc[c][r] = rec_coord[((long)b * NR + r0 + r) * 3 + c];
    }
    __syncthreads();

    // ---- compute ----
    const int lane = t & 63;
    const int wv   = t >> 6;
    const int q    = lane >> 4;        // quad 0..3
    const int n    = lane & 15;
    const float inv_s   = 8.0f / 3.0f;     // 1/0.375 (sign of sigma irrelevant)
    const float mu_step = 12.0f / 31.0f;   // linspace(0,12,32) spacing

    float sum = 0.0f;

    const int NTILES = (NL / 16) * (RT / 16);   // 8*4 = 32
    for (int tile = wv; tile < NTILES; tile += NTHREADS / 64) {
        const int tl = tile >> 2;   // 0..7 over L
        const int tr = tile & 3;    // 0..3 over RT
        // distances for this lane's 4 C elements: row l = tl*16+q*4+i, col r = tr*16+n
        const int rr = tr * 16 + n;
        const float rx = sRc[0][rr], ry = sRc[1][rr], rz = sRc[2][rr];
        float d[4];
        #pragma unroll
        for (int i = 0; i < 4; ++i) {
            const int ll = tl * 16 + q * 4 + i;
            const float dx = sLc[0][ll] - rx;
            const float dy = sLc[1][ll] - ry;
            const float dz = sLc[2][ll] - rz;
            d[i] = sqrtf(dx * dx + dy * dy + dz * dz);
        }
        // fragment addresses (A: m = lane&15, k = q*8+j ; B symmetric)
        const int arow = (tl * 16 + n) * NF;
        const int brow = (tr * 16 + n) * NF;
        const int h  = n & 7;
        const int c0 = ((q ^ h) << 3);         // chunk q     (f 0..31 slice)
        const int c1 = (((4 + q) ^ h) << 3);   // chunk q+4   (f 32..63 slice)

        #pragma unroll
        for (int ke = 0; ke < EG; ++ke) {
            const s16x8 a0 = *(const s16x8*)&sA[ke][arow + c0];
            const s16x8 a1 = *(const s16x8*)&sA[ke][arow + c1];
            const s16x8 b0 = *(const s16x8*)&sB[ke][brow + c0];
            const s16x8 b1 = *(const s16x8*)&sB[ke][brow + c1];
            f32x4 acc = {0.f, 0.f, 0.f, 0.f};
            acc = __builtin_amdgcn_mfma_f32_16x16x32_bf16(a0, b0, acc, 0, 0, 0);
            acc = __builtin_amdgcn_mfma_f32_16x16x32_bf16(a1, b1, acc, 0, 0, 0);
            const float mu = (float)(e0 + ke) * mu_step;
            #pragma unroll
            for (int i = 0; i < 4; ++i) {
                const float z = (d[i] - mu) * inv_s;
                sum += __expf(-z * z) * acc[i];   // rbf weight * atn
            }
        }
    }

    // ---- reduce: wave -> block -> global atomic ----
    sum *= 0.01f;   // ENERGY_SCALE
    #pragma unroll
    for (int off = 32; off > 0; off >>= 1)
        sum += __shfl_down(sum, off, 64);
    if (lane == 0) sRed[wv] = sum;
    __syncthreads();
    if (t == 0)
        atomicAdd(&out[b], sRed[0] + sRed[1] + sRed[2] + sRed[3]);
}

extern "C" void kernel_launch(void* const* d_in, const int* in_sizes, int n_in,
                              void* d_out, int out_size, void* d_ws, size_t ws_size,
                              hipStream_t stream) {
    const float* lig_feat  = (const float*)d_in[0];
    const float* rec_feat  = (const float*)d_in[1];
    const float* lig_coord = (const float*)d_in[2];
    const float* rec_coord = (const float*)d_in[3];
    float* out = (float*)d_out;

    // d_out is poisoned 0xAA before every timed launch; zero it (capture-safe)
    hipMemsetAsync(out, 0, (size_t)out_size * sizeof(float), stream);

    dim3 grid(NB * NRT * NEG);   // 4096
    ff_kernel<<<grid, NTHREADS, 0, stream>>>(lig_feat, rec_feat,
                                             lig_coord, rec_coord, out);
}

// Round 2
// 214.342 us; speedup vs baseline: 1.2644x; 1.2644x over previous
//
#include <hip/hip_runtime.h>
#include <hip/hip_bf16.h>

// B=8, L=128, R=2048, E=32, F=64
#define NB 8
#define NL 128
#define NR 2048
#define NE 32
#define NF 64
#define RT 64                 // r-tile per block
#define EG 2                  // e's staged per iteration
#define NEP (NE / EG)         // 16 e-pair iterations
#define NRT (NR / RT)         // 32 r-tiles
#define NTHREADS 512
#define NWAVES (NTHREADS / 64)

typedef __attribute__((ext_vector_type(4)))  float f32x4;
typedef __attribute__((ext_vector_type(16))) float f32x16;
typedef __attribute__((ext_vector_type(8)))  short s16x8;

__device__ __forceinline__ unsigned short f2bf(float x) {
    union { float f; unsigned u; } v; v.f = x;
    unsigned u = v.u;
    u += 0x7fffu + ((u >> 16) & 1u);   // RNE
    return (unsigned short)(u >> 16);
}

__device__ __forceinline__ unsigned long long pack4(f32x4 v) {
    unsigned long long lo = (unsigned)f2bf(v.x) | ((unsigned)f2bf(v.y) << 16);
    unsigned long long hi = (unsigned)f2bf(v.z) | ((unsigned)f2bf(v.w) << 16);
    return lo | (hi << 32);
}

__global__ __launch_bounds__(NTHREADS) void ff_kernel(
    const float* __restrict__ lig_feat,
    const float* __restrict__ rec_feat,
    const float* __restrict__ lig_coord,
    const float* __restrict__ rec_coord,
    float* __restrict__ out)
{
    // double-buffered bf16 tiles; rows of 64 elems = 8 chunks of 16B,
    // chunk XOR-swizzled by (row&7)
    __shared__ __align__(16) unsigned short sA[2][EG * NL * NF];  // 2 x 32 KB
    __shared__ __align__(16) unsigned short sB[2][EG * RT * NF];  // 2 x 16 KB
    __shared__ float sLc[3][NL];
    __shared__ float sRc[3][RT];
    __shared__ float sRed[NWAVES];

    const int blk = blockIdx.x;
    const int rt  = blk & (NRT - 1);
    const int b   = blk >> 5;
    const int r0  = rt * RT;
    const int t   = threadIdx.x;
    const int lane = t & 63;
    const int wv   = t >> 6;

    // ---- coords to LDS ----
    for (int i = t; i < 3 * NL; i += NTHREADS) {
        const int c = i >> 7, l = i & 127;
        sLc[c][l] = lig_coord[((long)b * NL + l) * 3 + c];
    }
    for (int i = t; i < 3 * RT; i += NTHREADS) {
        const int c = i >> 6, r = i & 63;
        sRc[c][r] = rec_coord[((long)b * NR + r0 + r) * 3 + c];
    }

    // ---- stage e-pair 0 into buffer 0 ----
    {
        #pragma unroll
        for (int j = 0; j < 8; ++j) {
            const int idx = t + NTHREADS * j;             // 0..4095
            const int f4 = idx & 15, l = (idx >> 4) & 127, ke = idx >> 11;
            f32x4 v = *(const f32x4*)(lig_feat + (((long)b * NL + l) * NE + ke) * NF + f4 * 4);
            const int pos = (((f4 >> 1) ^ (l & 7)) << 3) + ((f4 & 1) << 2);
            *(unsigned long long*)&sA[0][ke * NL * NF + l * NF + pos] = pack4(v);
        }
        #pragma unroll
        for (int j = 0; j < 4; ++j) {
            const int idx = t + NTHREADS * j;             // 0..2047
            const int f4 = idx & 15, r = (idx >> 4) & 63, ke = idx >> 10;
            f32x4 v = *(const f32x4*)(rec_feat + (((long)b * NR + r0 + r) * NE + ke) * NF + f4 * 4);
            const int pos = (((f4 >> 1) ^ (r & 7)) << 3) + ((f4 & 1) << 2);
            *(unsigned long long*)&sB[0][ke * RT * NF + r * NF + pos] = pack4(v);
        }
    }
    __syncthreads();

    // ---- per-wave 32x32 tile; distances once, kept in registers ----
    const int tl = wv >> 1;            // 0..3 over L
    const int tr = wv & 1;             // 0..1 over RT
    const int n  = lane & 31;
    const int h  = lane >> 5;
    const int colr = tr * 32 + n;
    const float rx = sRc[0][colr], ry = sRc[1][colr], rz = sRc[2][colr];
    float d[16];
    #pragma unroll
    for (int i = 0; i < 16; ++i) {
        const int row = tl * 32 + 4 * h + (i & 3) + ((i >> 2) << 3);
        const float dx = sLc[0][row] - rx;
        const float dy = sLc[1][row] - ry;
        const float dz = sLc[2][row] - rz;
        d[i] = sqrtf(dx * dx + dy * dy + dz * dz);
    }

    const float inv_s   = 32.0f / 12.0f;
    const float mu_step = 12.0f / 31.0f;
    const int aBase = (tl * 32 + n) * NF;   // A row base (elem units)
    const int bBase = (tr * 32 + n) * NF;   // B row base
    const int sw = (n & 7);                 // row swizzle key (rows % 8 == n % 8)

    float sum = 0.0f;

    for (int ep = 0; ep < NEP; ++ep) {
        const int cur = ep & 1;

        // -- issue global loads for next e-pair (hide latency behind compute) --
        f32x4 tA[8]; f32x4 tB[4];
        const int e0n = (ep + 1) * EG;
        if (ep + 1 < NEP) {
            #pragma unroll
            for (int j = 0; j < 8; ++j) {
                const int idx = t + NTHREADS * j;
                const int f4 = idx & 15, l = (idx >> 4) & 127, ke = idx >> 11;
                tA[j] = *(const f32x4*)(lig_feat + (((long)b * NL + l) * NE + e0n + ke) * NF + f4 * 4);
            }
            #pragma unroll
            for (int j = 0; j < 4; ++j) {
                const int idx = t + NTHREADS * j;
                const int f4 = idx & 15, r = (idx >> 4) & 63, ke = idx >> 10;
                tB[j] = *(const f32x4*)(rec_feat + (((long)b * NR + r0 + r) * NE + e0n + ke) * NF + f4 * 4);
            }
        }

        // -- compute on current buffer --
        #pragma unroll
        for (int ke = 0; ke < EG; ++ke) {
            const unsigned short* pa = &sA[cur][ke * NL * NF + aBase];
            const unsigned short* pb = &sB[cur][ke * RT * NF + bBase];
            f32x16 acc = {0,0,0,0,0,0,0,0,0,0,0,0,0,0,0,0};
            #pragma unroll
            for (int kc = 0; kc < 4; ++kc) {
                const int ck = kc * 2 + h;               // 16B chunk (k-slice)
                const s16x8 af = *(const s16x8*)&pa[(ck ^ sw) << 3];
                const s16x8 bf = *(const s16x8*)&pb[(ck ^ sw) << 3];
                acc = __builtin_amdgcn_mfma_f32_32x32x16_bf16(af, bf, acc, 0, 0, 0);
            }
            const float mu = (float)(ep * EG + ke) * mu_step;
            #pragma unroll
            for (int i = 0; i < 16; ++i) {
                const float z = (d[i] - mu) * inv_s;
                sum += __expf(-z * z) * acc[i];
            }
        }

        // -- convert + write next buffer --
        if (ep + 1 < NEP) {
            #pragma unroll
            for (int j = 0; j < 8; ++j) {
                const int idx = t + NTHREADS * j;
                const int f4 = idx & 15, l = (idx >> 4) & 127, ke = idx >> 11;
                const int pos = (((f4 >> 1) ^ (l & 7)) << 3) + ((f4 & 1) << 2);
                *(unsigned long long*)&sA[cur ^ 1][ke * NL * NF + l * NF + pos] = pack4(tA[j]);
            }
            #pragma unroll
            for (int j = 0; j < 4; ++j) {
                const int idx = t + NTHREADS * j;
                const int f4 = idx & 15, r = (idx >> 4) & 63, ke = idx >> 10;
                const int pos = (((f4 >> 1) ^ (r & 7)) << 3) + ((f4 & 1) << 2);
                *(unsigned long long*)&sB[cur ^ 1][ke * RT * NF + r * NF + pos] = pack4(tB[j]);
            }
        }
        __syncthreads();
    }

    // ---- reduce: wave -> block -> global atomic ----
    sum *= 0.01f;   // ENERGY_SCALE
    #pragma unroll
    for (int off = 32; off > 0; off >>= 1)
        sum += __shfl_down(sum, off, 64);
    if (lane == 0) sRed[wv] = sum;
    __syncthreads();
    if (t == 0) {
        float s = 0.f;
        #pragma unroll
        for (int w = 0; w < NWAVES; ++w) s += sRed[w];
        atomicAdd(&out[b], s);
    }
}

extern "C" void kernel_launch(void* const* d_in, const int* in_sizes, int n_in,
                              void* d_out, int out_size, void* d_ws, size_t ws_size,
                              hipStream_t stream) {
    const float* lig_feat  = (const float*)d_in[0];
    const float* rec_feat  = (const float*)d_in[1];
    const float* lig_coord = (const float*)d_in[2];
    const float* rec_coord = (const float*)d_in[3];
    float* out = (float*)d_out;

    hipMemsetAsync(out, 0, (size_t)out_size * sizeof(float), stream);

    dim3 grid(NB * NRT);   // 256 blocks: (b, r-tile)
    ff_kernel<<<grid, NTHREADS, 0, stream>>>(lig_feat, rec_feat,
                                             lig_coord, rec_coord, out);
}

// Round 3
// 208.182 us; speedup vs baseline: 1.3018x; 1.0296x over previous
//
#include <hip/hip_runtime.h>
#include <hip/hip_bf16.h>

// B=8, L=128, R=2048, E=32, F=64
#define NB 8
#define NL 128
#define NR 2048
#define NE 32
#define NF 64
#define RT 256                // r-rows per block
#define NRT (NR / RT)         // 8 r-tiles
#define EH 4                  // e-groups (blocks) per (b, rt)
#define EPB (NE / EH)         // 8 e's per block
#define NTHREADS 1024
#define NWAVES (NTHREADS / 64)

typedef __attribute__((ext_vector_type(4)))  float f32x4;
typedef __attribute__((ext_vector_type(16))) float f32x16;
typedef __attribute__((ext_vector_type(8)))  short s16x8;

__device__ __forceinline__ unsigned short f2bf(float x) {
    union { float f; unsigned u; } v; v.f = x;
    unsigned u = v.u;
    u += 0x7fffu + ((u >> 16) & 1u);   // RNE
    return (unsigned short)(u >> 16);
}

__device__ __forceinline__ unsigned long long pack4(f32x4 v) {
    unsigned long long lo = (unsigned)f2bf(v.x) | ((unsigned)f2bf(v.y) << 16);
    unsigned long long hi = (unsigned)f2bf(v.z) | ((unsigned)f2bf(v.w) << 16);
    return lo | (hi << 32);
}

__global__ __launch_bounds__(NTHREADS) void ff_kernel(
    const float* __restrict__ lig_feat,
    const float* __restrict__ rec_feat,
    const float* __restrict__ lig_coord,
    const float* __restrict__ rec_coord,
    float* __restrict__ out)
{
    // bf16 tiles, rows of 64 elems = 8 x 16B chunks, chunk XOR-swizzled by (row&7)
    __shared__ __align__(16) unsigned short sA[2][NL * NF];  // 2 x 16 KB
    __shared__ __align__(16) unsigned short sB[2][RT * NF];  // 2 x 32 KB
    __shared__ float sLc[3][NL];
    __shared__ float sRc[3][RT];
    __shared__ float sRed[NWAVES];

    const int blk = blockIdx.x;
    const int eh  = blk & (EH - 1);
    const int rt  = (blk >> 2) & (NRT - 1);
    const int b   = blk >> 5;            // 8*8*4 = 256 blocks
    const int e0  = eh * EPB;
    const int r0  = rt * RT;
    const int t   = threadIdx.x;
    const int lane = t & 63;
    const int wv   = t >> 6;

    // ---- coords to LDS ----
    for (int i = t; i < 3 * NL; i += NTHREADS) {
        const int c = i >> 7, l = i & 127;
        sLc[c][l] = lig_coord[((long)b * NL + l) * 3 + c];
    }
    for (int i = t; i < 3 * RT; i += NTHREADS) {
        const int c = i >> 8, r = i & 255;
        sRc[c][r] = rec_coord[((long)b * NR + r0 + r) * 3 + c];
    }

    // ---- stage e0 into buffer 0 ----
    {
        #pragma unroll
        for (int j = 0; j < 2; ++j) {                // lig: 2048 float4
            const int idx = t + NTHREADS * j;
            const int f4 = idx & 15, l = idx >> 4;
            f32x4 v = *(const f32x4*)(lig_feat + (((long)b * NL + l) * NE + e0) * NF + f4 * 4);
            const int pos = (((f4 >> 1) ^ (l & 7)) << 3) + ((f4 & 1) << 2);
            *(unsigned long long*)&sA[0][l * NF + pos] = pack4(v);
        }
        #pragma unroll
        for (int j = 0; j < 4; ++j) {                // rec: 4096 float4
            const int idx = t + NTHREADS * j;
            const int f4 = idx & 15, r = idx >> 4;
            f32x4 v = *(const f32x4*)(rec_feat + (((long)b * NR + r0 + r) * NE + e0) * NF + f4 * 4);
            const int pos = (((f4 >> 1) ^ (r & 7)) << 3) + ((f4 & 1) << 2);
            *(unsigned long long*)&sB[0][r * NF + pos] = pack4(v);
        }
    }
    __syncthreads();

    // ---- per-wave: two 32x32 tiles (same r-column strip), distances in regs ----
    const int n  = lane & 31;
    const int h  = lane >> 5;
    const int tr = wv & 7;               // 0..7 over RT/32
    const int tl0 = wv >> 3;             // tile0: tl0, tile1: tl0+2
    const int colr = tr * 32 + n;
    const float rx = sRc[0][colr], ry = sRc[1][colr], rz = sRc[2][colr];
    float d[2][16];
    #pragma unroll
    for (int t2 = 0; t2 < 2; ++t2) {
        const int tl = tl0 + 2 * t2;
        #pragma unroll
        for (int i = 0; i < 16; ++i) {
            const int row = tl * 32 + 4 * h + (i & 3) + ((i >> 2) << 3);
            const float dx = sLc[0][row] - rx;
            const float dy = sLc[1][row] - ry;
            const float dz = sLc[2][row] - rz;
            d[t2][i] = sqrtf(dx * dx + dy * dy + dz * dz);
        }
    }

    const float inv_s   = 32.0f / 12.0f;
    const float mu_step = 12.0f / 31.0f;
    const int sw = (n & 7);
    const int bBase = (tr * 32 + n) * NF;

    float sum = 0.0f;

    for (int ep = 0; ep < EPB; ++ep) {
        const int cur = ep & 1;

        // -- prefetch next e into registers --
        f32x4 tA[2]; f32x4 tB[4];
        const int en = e0 + ep + 1;
        if (ep + 1 < EPB) {
            #pragma unroll
            for (int j = 0; j < 2; ++j) {
                const int idx = t + NTHREADS * j;
                const int f4 = idx & 15, l = idx >> 4;
                tA[j] = *(const f32x4*)(lig_feat + (((long)b * NL + l) * NE + en) * NF + f4 * 4);
            }
            #pragma unroll
            for (int j = 0; j < 4; ++j) {
                const int idx = t + NTHREADS * j;
                const int f4 = idx & 15, r = idx >> 4;
                tB[j] = *(const f32x4*)(rec_feat + (((long)b * NR + r0 + r) * NE + en) * NF + f4 * 4);
            }
        }

        // -- compute on current buffer --
        const float mu = (float)(e0 + ep) * mu_step;
        #pragma unroll
        for (int t2 = 0; t2 < 2; ++t2) {
            const int tl = tl0 + 2 * t2;
            const unsigned short* pa = &sA[cur][(tl * 32 + n) * NF];
            const unsigned short* pb = &sB[cur][bBase];
            f32x16 acc = {0,0,0,0,0,0,0,0,0,0,0,0,0,0,0,0};
            #pragma unroll
            for (int kc = 0; kc < 4; ++kc) {
                const int ck = kc * 2 + h;
                const s16x8 af = *(const s16x8*)&pa[(ck ^ sw) << 3];
                const s16x8 bf = *(const s16x8*)&pb[(ck ^ sw) << 3];
                acc = __builtin_amdgcn_mfma_f32_32x32x16_bf16(af, bf, acc, 0, 0, 0);
            }
            #pragma unroll
            for (int i = 0; i < 16; ++i) {
                const float z = (d[t2][i] - mu) * inv_s;
                sum += __expf(-z * z) * acc[i];
            }
        }

        // -- convert + write next buffer --
        if (ep + 1 < EPB) {
            #pragma unroll
            for (int j = 0; j < 2; ++j) {
                const int idx = t + NTHREADS * j;
                const int f4 = idx & 15, l = idx >> 4;
                const int pos = (((f4 >> 1) ^ (l & 7)) << 3) + ((f4 & 1) << 2);
                *(unsigned long long*)&sA[cur ^ 1][l * NF + pos] = pack4(tA[j]);
            }
            #pragma unroll
            for (int j = 0; j < 4; ++j) {
                const int idx = t + NTHREADS * j;
                const int f4 = idx & 15, r = idx >> 4;
                const int pos = (((f4 >> 1) ^ (r & 7)) << 3) + ((f4 & 1) << 2);
                *(unsigned long long*)&sB[cur ^ 1][r * NF + pos] = pack4(tB[j]);
            }
        }
        __syncthreads();
    }

    // ---- reduce: wave -> block -> global atomic ----
    sum *= 0.01f;   // ENERGY_SCALE
    #pragma unroll
    for (int off = 32; off > 0; off >>= 1)
        sum += __shfl_down(sum, off, 64);
    if (lane == 0) sRed[wv] = sum;
    __syncthreads();
    if (t == 0) {
        float s = 0.f;
        #pragma unroll
        for (int w = 0; w < NWAVES; ++w) s += sRed[w];
        atomicAdd(&out[b], s);
    }
}

extern "C" void kernel_launch(void* const* d_in, const int* in_sizes, int n_in,
                              void* d_out, int out_size, void* d_ws, size_t ws_size,
                              hipStream_t stream) {
    const float* lig_feat  = (const float*)d_in[0];
    const float* rec_feat  = (const float*)d_in[1];
    const float* lig_coord = (const float*)d_in[2];
    const float* rec_coord = (const float*)d_in[3];
    float* out = (float*)d_out;

    hipMemsetAsync(out, 0, (size_t)out_size * sizeof(float), stream);

    dim3 grid(NB * NRT * EH);   // 256 blocks: (b, r-tile, e-group)
    ff_kernel<<<grid, NTHREADS, 0, stream>>>(lig_feat, rec_feat,
                                             lig_coord, rec_coord, out);
}

// Round 4
// 207.720 us; speedup vs baseline: 1.3047x; 1.0022x over previous
//
#include <hip/hip_runtime.h>
#include <hip/hip_bf16.h>

// B=8, L=128, R=2048, E=32, F=64
#define NB 8
#define NL 128
#define NR 2048
#define NE 32
#define NF 64
#define RT 128                // r-rows per block
#define NRT (NR / RT)         // 16 r-tiles
#define EH 4                  // e-groups (blocks) per (b, rt)
#define EPB (NE / EH)         // 8 e's per block
#define NTHREADS 512
#define NWAVES (NTHREADS / 64)

typedef __attribute__((ext_vector_type(4)))  float f32x4;
typedef __attribute__((ext_vector_type(16))) float f32x16;
typedef __attribute__((ext_vector_type(8)))  short s16x8;

__device__ __forceinline__ unsigned short f2bf(float x) {
    union { float f; unsigned u; } v; v.f = x;
    unsigned u = v.u;
    u += 0x7fffu + ((u >> 16) & 1u);   // RNE
    return (unsigned short)(u >> 16);
}

__device__ __forceinline__ unsigned long long pack4(f32x4 v) {
    unsigned long long lo = (unsigned)f2bf(v.x) | ((unsigned)f2bf(v.y) << 16);
    unsigned long long hi = (unsigned)f2bf(v.z) | ((unsigned)f2bf(v.w) << 16);
    return lo | (hi << 32);
}

// 2 blocks/CU: 512 threads, ~68 KB LDS, VGPR capped at 128 (4 waves/SIMD)
__global__ __launch_bounds__(NTHREADS, 4) void ff_kernel(
    const float* __restrict__ lig_feat,
    const float* __restrict__ rec_feat,
    const float* __restrict__ lig_coord,
    const float* __restrict__ rec_coord,
    float* __restrict__ out)
{
    // bf16 tiles; rows of 64 elems = 8 x 16B chunks, chunk XOR-swizzled by (row&7)
    __shared__ __align__(16) unsigned short sA[2][NL * NF];  // 2 x 16 KB
    __shared__ __align__(16) unsigned short sB[2][RT * NF];  // 2 x 16 KB
    __shared__ float sLc[3][NL];
    __shared__ float sRc[3][RT];
    __shared__ float sRed[NWAVES];

    const int blk = blockIdx.x;
    const int eh  = blk & (EH - 1);
    const int rt  = (blk >> 2) & (NRT - 1);
    const int b   = blk >> 6;            // 8*16*4 = 512 blocks
    const int e0  = eh * EPB;
    const int r0  = rt * RT;
    const int t   = threadIdx.x;
    const int lane = t & 63;
    const int wv   = t >> 6;

    // ---- coords to LDS + issue e0 feature loads ----
    for (int i = t; i < 3 * NL; i += NTHREADS) {
        const int c = i >> 7, l = i & 127;
        sLc[c][l] = lig_coord[((long)b * NL + l) * 3 + c];
    }
    for (int i = t; i < 3 * RT; i += NTHREADS) {
        const int c = i >> 7, r = i & 127;
        sRc[c][r] = rec_coord[((long)b * NR + r0 + r) * 3 + c];
    }

    f32x4 tA[4], tB[4];
    #pragma unroll
    for (int j = 0; j < 4; ++j) {                // lig: 2048 float4
        const int idx = t + NTHREADS * j;
        const int f4 = idx & 15, l = idx >> 4;
        tA[j] = *(const f32x4*)(lig_feat + (((long)b * NL + l) * NE + e0) * NF + f4 * 4);
    }
    #pragma unroll
    for (int j = 0; j < 4; ++j) {                // rec: 2048 float4
        const int idx = t + NTHREADS * j;
        const int f4 = idx & 15, r = idx >> 4;
        tB[j] = *(const f32x4*)(rec_feat + (((long)b * NR + r0 + r) * NE + e0) * NF + f4 * 4);
    }
    __syncthreads();   // coords visible

    // ---- per-wave: two 32x32 tiles (same r-strip), distances once in regs ----
    const int n  = lane & 31;
    const int h  = lane >> 5;
    const int tr  = wv & 3;              // 0..3 over RT/32
    const int tl0 = wv >> 2;             // tile0: tl0, tile1: tl0+2
    const int colr = tr * 32 + n;
    const float rx = sRc[0][colr], ry = sRc[1][colr], rz = sRc[2][colr];
    float d[2][16];
    #pragma unroll
    for (int t2 = 0; t2 < 2; ++t2) {
        const int tl = tl0 + 2 * t2;
        #pragma unroll
        for (int i = 0; i < 16; ++i) {
            const int row = tl * 32 + 4 * h + (i & 3) + ((i >> 2) << 3);
            const float dx = sLc[0][row] - rx;
            const float dy = sLc[1][row] - ry;
            const float dz = sLc[2][row] - rz;
            d[t2][i] = sqrtf(dx * dx + dy * dy + dz * dz);
        }
    }

    // ---- write e0 into buf0, prefetch e1 into regs ----
    #pragma unroll
    for (int j = 0; j < 4; ++j) {
        const int idx = t + NTHREADS * j;
        const int f4 = idx & 15, l = idx >> 4;
        const int pos = (((f4 >> 1) ^ (l & 7)) << 3) + ((f4 & 1) << 2);
        *(unsigned long long*)&sA[0][l * NF + pos] = pack4(tA[j]);
    }
    #pragma unroll
    for (int j = 0; j < 4; ++j) {
        const int idx = t + NTHREADS * j;
        const int f4 = idx & 15, r = idx >> 4;
        const int pos = (((f4 >> 1) ^ (r & 7)) << 3) + ((f4 & 1) << 2);
        *(unsigned long long*)&sB[0][r * NF + pos] = pack4(tB[j]);
    }
    if (EPB > 1) {
        #pragma unroll
        for (int j = 0; j < 4; ++j) {
            const int idx = t + NTHREADS * j;
            const int f4 = idx & 15, l = idx >> 4;
            tA[j] = *(const f32x4*)(lig_feat + (((long)b * NL + l) * NE + e0 + 1) * NF + f4 * 4);
        }
        #pragma unroll
        for (int j = 0; j < 4; ++j) {
            const int idx = t + NTHREADS * j;
            const int f4 = idx & 15, r = idx >> 4;
            tB[j] = *(const f32x4*)(rec_feat + (((long)b * NR + r0 + r) * NE + e0 + 1) * NF + f4 * 4);
        }
    }
    __syncthreads();   // buf0 visible

    const float inv_s   = 32.0f / 12.0f;
    const float mu_step = 12.0f / 31.0f;
    const int sw = (n & 7);
    const int aBase = (tl0 * 32 + n) * NF;   // tile0 A row; tile1 at +64*NF
    const int bBase = (tr * 32 + n) * NF;

    float sum = 0.0f;

    for (int ep = 0; ep < EPB; ++ep) {
        const int cur = ep & 1;

        // -- write regs (holding e_{ep+1}) into other buffer; then reload regs
        //    with e_{ep+2} (consumed next ep, a full phase of latency slack) --
        if (ep + 1 < EPB) {
            #pragma unroll
            for (int j = 0; j < 4; ++j) {
                const int idx = t + NTHREADS * j;
                const int f4 = idx & 15, l = idx >> 4;
                const int pos = (((f4 >> 1) ^ (l & 7)) << 3) + ((f4 & 1) << 2);
                *(unsigned long long*)&sA[cur ^ 1][l * NF + pos] = pack4(tA[j]);
            }
            #pragma unroll
            for (int j = 0; j < 4; ++j) {
                const int idx = t + NTHREADS * j;
                const int f4 = idx & 15, r = idx >> 4;
                const int pos = (((f4 >> 1) ^ (r & 7)) << 3) + ((f4 & 1) << 2);
                *(unsigned long long*)&sB[cur ^ 1][r * NF + pos] = pack4(tB[j]);
            }
        }
        if (ep + 2 < EPB) {
            const int en = e0 + ep + 2;
            #pragma unroll
            for (int j = 0; j < 4; ++j) {
                const int idx = t + NTHREADS * j;
                const int f4 = idx & 15, l = idx >> 4;
                tA[j] = *(const f32x4*)(lig_feat + (((long)b * NL + l) * NE + en) * NF + f4 * 4);
            }
            #pragma unroll
            for (int j = 0; j < 4; ++j) {
                const int idx = t + NTHREADS * j;
                const int f4 = idx & 15, r = idx >> 4;
                tB[j] = *(const f32x4*)(rec_feat + (((long)b * NR + r0 + r) * NE + en) * NF + f4 * 4);
            }
        }

        // -- compute on current buffer --
        const float mu = (float)(e0 + ep) * mu_step;
        #pragma unroll
        for (int t2 = 0; t2 < 2; ++t2) {
            const unsigned short* pa = &sA[cur][aBase + t2 * 64 * NF];
            const unsigned short* pb = &sB[cur][bBase];
            f32x16 acc = {0,0,0,0,0,0,0,0,0,0,0,0,0,0,0,0};
            #pragma unroll
            for (int kc = 0; kc < 4; ++kc) {
                const int ck = kc * 2 + h;
                const s16x8 af = *(const s16x8*)&pa[(ck ^ sw) << 3];
                const s16x8 bf = *(const s16x8*)&pb[(ck ^ sw) << 3];
                acc = __builtin_amdgcn_mfma_f32_32x32x16_bf16(af, bf, acc, 0, 0, 0);
            }
            #pragma unroll
            for (int i = 0; i < 16; ++i) {
                const float z = (d[t2][i] - mu) * inv_s;
                sum += __expf(-z * z) * acc[i];
            }
        }

        if (ep + 1 < EPB) __syncthreads();
    }

    // ---- reduce: wave -> block -> global atomic ----
    sum *= 0.01f;   // ENERGY_SCALE
    #pragma unroll
    for (int off = 32; off > 0; off >>= 1)
        sum += __shfl_down(sum, off, 64);
    if (lane == 0) sRed[wv] = sum;
    __syncthreads();
    if (t == 0) {
        float s = 0.f;
        #pragma unroll
        for (int w = 0; w < NWAVES; ++w) s += sRed[w];
        atomicAdd(&out[b], s);
    }
}

extern "C" void kernel_launch(void* const* d_in, const int* in_sizes, int n_in,
                              void* d_out, int out_size, void* d_ws, size_t ws_size,
                              hipStream_t stream) {
    const float* lig_feat  = (const float*)d_in[0];
    const float* rec_feat  = (const float*)d_in[1];
    const float* lig_coord = (const float*)d_in[2];
    const float* rec_coord = (const float*)d_in[3];
    float* out = (float*)d_out;

    hipMemsetAsync(out, 0, (size_t)out_size * sizeof(float), stream);

    dim3 grid(NB * NRT * EH);   // 512 blocks: (b, r-tile, e-group)
    ff_kernel<<<grid, NTHREADS, 0, stream>>>(lig_feat, rec_feat,
                                             lig_coord, rec_coord, out);
}